// Round 1
// baseline (185.381 us; speedup 1.0000x reference)
//
#include <hip/hip_runtime.h>
#include <math.h>

// Weights / constants from the reference
#define INSIDE_W   0.5f
#define OUTSIDE_W  2.0f
#define CONTACT_W  0.5f
#define HCP_W      1.0f
#define POSE_W     0.01f
#define HANDPOSE_W 0.01f
#define ANGLE_W    0.1f
#define A1c 0.04f
#define A2c 0.04f
#define B1c 0.07f
#define B2c 0.06f
#define C1c 0.01f
#define C2c 0.01f
#define D1c 0.023f
#define D2c 0.02f

__device__ __forceinline__ float waveReduceSum(float x) {
#pragma unroll
    for (int o = 32; o > 0; o >>= 1) x += __shfl_down(x, o, 64);
    return x;
}
__device__ __forceinline__ float waveReduceMin(float x) {
#pragma unroll
    for (int o = 32; o > 0; o >>= 1) x = fminf(x, __shfl_down(x, o, 64));
    return x;
}

// Accumulator slots in ws (floats):
// 0: outside_sum
// 1: contact_sum  2: contact_cnt
// 3: inside_sum   4: inside_cnt
// 5: lout_sum     6: lout_cnt
// 7: rout_sum     8: rout_cnt
// 9: lin_sum     10: lin_cnt
// 11: rin_sum    12: rin_cnt
// 13: ag_sum     14: close_cnt
// 15,16,17: nbar_sum xyz

// K1: gdi[v] = min_j geodist[v, ivc[j]]; fused outsideloss partial.
__global__ __launch_bounds__(256) void k_gdi(
    const float* __restrict__ geodist, const int* __restrict__ ivc,
    const float* __restrict__ verts, const float* __restrict__ iverts,
    float* __restrict__ gdi, float* __restrict__ accum, int NV, int NC)
{
    int v = blockIdx.x;
    const float* row = geodist + (size_t)v * (size_t)NV;
    float m = 3.4e38f;
    for (int j = threadIdx.x; j < NC; j += 256) {
        int c = ivc[j];
        m = fminf(m, row[c]);
    }
    m = waveReduceMin(m);
    __shared__ float sm[4];
    int lane = threadIdx.x & 63;
    int w = threadIdx.x >> 6;
    if (lane == 0) sm[w] = m;
    __syncthreads();
    if (threadIdx.x == 0) {
        float g = fminf(fminf(sm[0], sm[1]), fminf(sm[2], sm[3]));
        gdi[v] = g;
        float dx = iverts[v * 3 + 0] - verts[v * 3 + 0];
        float dy = iverts[v * 3 + 1] - verts[v * 3 + 1];
        float dz = iverts[v * 3 + 2] - verts[v * 3 + 2];
        float v2v0 = sqrtf(dx * dx + dy * dy + dz * dz);
        float w0 = 2.0f * g;
        w0 *= w0;
        atomicAdd(&accum[0], v2v0 * w0);
    }
}

// K2: face normals scatter-add + inside[] scatter.
__global__ __launch_bounds__(256) void k_faces(
    const float* __restrict__ verts, const int* __restrict__ faces,
    float* __restrict__ vn, const int* __restrict__ ds,
    const int* __restrict__ exterior, int* __restrict__ inside,
    int NF, int NDS)
{
    int t = blockIdx.x * blockDim.x + threadIdx.x;
    if (t < NF) {
        int i0 = faces[t * 3 + 0];
        int i1 = faces[t * 3 + 1];
        int i2 = faces[t * 3 + 2];
        float p0x = verts[i0 * 3 + 0], p0y = verts[i0 * 3 + 1], p0z = verts[i0 * 3 + 2];
        float ax = verts[i1 * 3 + 0] - p0x;
        float ay = verts[i1 * 3 + 1] - p0y;
        float az = verts[i1 * 3 + 2] - p0z;
        float bx = verts[i2 * 3 + 0] - p0x;
        float by = verts[i2 * 3 + 1] - p0y;
        float bz = verts[i2 * 3 + 2] - p0z;
        float nx = ay * bz - az * by;
        float ny = az * bx - ax * bz;
        float nz = ax * by - ay * bx;
        atomicAdd(&vn[i0 * 3 + 0], nx);
        atomicAdd(&vn[i0 * 3 + 1], ny);
        atomicAdd(&vn[i0 * 3 + 2], nz);
        atomicAdd(&vn[i1 * 3 + 0], nx);
        atomicAdd(&vn[i1 * 3 + 1], ny);
        atomicAdd(&vn[i1 * 3 + 2], nz);
        atomicAdd(&vn[i2 * 3 + 0], nx);
        atomicAdd(&vn[i2 * 3 + 1], ny);
        atomicAdd(&vn[i2 * 3 + 2], nz);
    }
    if (t < NDS) {
        inside[ds[t]] = exterior[t] ? 0 : 1;
    }
}

// K3: normalize vn in place; accumulate nbar sums.
__global__ __launch_bounds__(256) void k_normalize(
    float* __restrict__ vn, float* __restrict__ accum, int NV)
{
    int t = blockIdx.x * blockDim.x + threadIdx.x;
    float x = 0.f, y = 0.f, z = 0.f;
    if (t < NV) {
        x = vn[t * 3 + 0];
        y = vn[t * 3 + 1];
        z = vn[t * 3 + 2];
        float inv = 1.0f / (sqrtf(x * x + y * y + z * z) + 1e-12f);
        x *= inv; y *= inv; z *= inv;
        vn[t * 3 + 0] = x;
        vn[t * 3 + 1] = y;
        vn[t * 3 + 2] = z;
    }
    x = waveReduceSum(x);
    y = waveReduceSum(y);
    z = waveReduceSum(z);
    __shared__ float s[4][3];
    int lane = threadIdx.x & 63;
    int w = threadIdx.x >> 6;
    if (lane == 0) { s[w][0] = x; s[w][1] = y; s[w][2] = z; }
    __syncthreads();
    if (threadIdx.x < 3) {
        float v = s[0][threadIdx.x] + s[1][threadIdx.x] + s[2][threadIdx.x] + s[3][threadIdx.x];
        atomicAdd(&accum[15 + threadIdx.x], v);
    }
}

// K4: contact / inside / hand / angle masked sums.
__global__ __launch_bounds__(256) void k_terms(
    const float* __restrict__ v2v_min, const int* __restrict__ v2v_min_idx,
    const float* __restrict__ vn, const float* __restrict__ gdi,
    const int* __restrict__ ds, const int* __restrict__ exterior,
    const int* __restrict__ hcp, const float* __restrict__ hcpw,
    const int* __restrict__ inside, float* __restrict__ accum,
    int NV, int NDS, int HA)
{
    int t = blockIdx.x * blockDim.x + threadIdx.x;
    float a0 = 0.f, a1 = 0.f, a2 = 0.f, a3 = 0.f, a4 = 0.f, a5 = 0.f, a6 = 0.f;
    float a7 = 0.f, a8 = 0.f, a9 = 0.f, a10 = 0.f, a11 = 0.f, a12 = 0.f, a13 = 0.f;
    // angle term
    if (t < NV) {
        float vm = v2v_min[t];
        if (vm < 0.01f) {
            int idx = v2v_min_idx[t];
            float nbx = accum[15] / (float)NV;
            float nby = accum[16] / (float)NV;
            float nbz = accum[17] / (float)NV;
            float d = vn[idx * 3 + 0] * nbx + vn[idx * 3 + 1] * nby + vn[idx * 3 + 2] * nbz;
            a12 += 1.0f + d;  // ag_sum
            a13 += 1.0f;      // close_cnt
        }
    }
    // contact / inside terms over ds
    if (t < NDS) {
        int d = ds[t];
        int ext = exterior[t];
        float vm = v2v_min[d];
        if (ext) {
            float g = gdi[d];
            float wo = 1.0f / (5.0f * g + 1.0f);
            a0 += A1c * wo * tanhf(vm / A2c);  // contact_sum
            a1 += 1.0f;                        // contact_cnt
        } else {
            a2 += B1c * tanhf(vm / B2c);       // inside_sum
            a3 += 1.0f;                        // inside_cnt
        }
    }
    // hand contact terms
    if (t < HA) {
        int li = hcp[t];
        int ri = hcp[HA + t];
        float lw = 1.0f - 0.1f * hcpw[t];
        float rw = 1.0f - 0.1f * hcpw[HA + t];
        float lvm = v2v_min[li];
        float rvm = v2v_min[ri];
        if (inside[li]) {
            a8 += D1c * tanhf(lvm / D2c);      // lin_sum
            a9 += 1.0f;
        } else {
            a4 += lw * C1c * tanhf(lvm / C2c); // lout_sum
            a5 += 1.0f;
        }
        if (inside[ri]) {
            a10 += D1c * tanhf(rvm / D2c);     // rin_sum
            a11 += 1.0f;
        } else {
            a6 += rw * C1c * tanhf(rvm / C2c); // rout_sum
            a7 += 1.0f;
        }
    }
    // reduce 14 accumulators: wave shuffle then LDS
    float acc[14] = {a0, a1, a2, a3, a4, a5, a6, a7, a8, a9, a10, a11, a12, a13};
#pragma unroll
    for (int k = 0; k < 14; ++k) acc[k] = waveReduceSum(acc[k]);
    __shared__ float s[4][14];
    int lane = threadIdx.x & 63;
    int w = threadIdx.x >> 6;
    if (lane == 0) {
#pragma unroll
        for (int k = 0; k < 14; ++k) s[w][k] = acc[k];
    }
    __syncthreads();
    if (threadIdx.x < 14) {
        float v = s[0][threadIdx.x] + s[1][threadIdx.x] + s[2][threadIdx.x] + s[3][threadIdx.x];
        atomicAdd(&accum[1 + threadIdx.x], v);
    }
}

// K5: pose sums + final combine.
__global__ __launch_bounds__(128) void k_final(
    const float* __restrict__ accum,
    const float* __restrict__ bp, const float* __restrict__ ip,
    const float* __restrict__ lh, const float* __restrict__ rh,
    float* __restrict__ out)
{
    int t = threadIdx.x;
    float pose = 0.f, hand = 0.f;
    if (t < 63) {
        float d = bp[t] - ip[t];
        pose = d * d;
    }
    if (t < 45) {
        hand = lh[t] * lh[t] + rh[t] * rh[t];
    }
    pose = waveReduceSum(pose);
    hand = waveReduceSum(hand);
    __shared__ float s[2][2];
    int lane = t & 63;
    int w = t >> 6;
    if (lane == 0) { s[w][0] = pose; s[w][1] = hand; }
    __syncthreads();
    if (t == 0) {
        pose = s[0][0] + s[1][0];
        hand = s[0][1] + s[1][1];
        float contact_s = accum[1], contact_c = accum[2];
        float inside_s = accum[3], inside_c = accum[4];
        float lout_s = accum[5], lout_c = accum[6];
        float rout_s = accum[7], rout_c = accum[8];
        float lin_s = accum[9], lin_c = accum[10];
        float rin_s = accum[11], rin_c = accum[12];
        float ag_s = accum[13], close_c = accum[14];
        float contactloss = CONTACT_W * (contact_c > 0.f ? contact_s / contact_c : 0.f);
        float insideloss = INSIDE_W * (inside_c > 0.f ? inside_s / inside_c : 0.f);
        float hc_out = (lout_c > 0.f ? lout_s / lout_c : 0.f) + (rout_c > 0.f ? rout_s / rout_c : 0.f);
        float hc_in = (lin_c > 0.f ? lin_s / lin_c : 0.f) + (rin_c > 0.f ? rin_s / rin_c : 0.f);
        float hand_contact_loss = HCP_W * (hc_in + hc_out);
        float angle_loss = ANGLE_W * (close_c > 0.f ? ag_s / close_c : 0.f);
        float outsideloss = OUTSIDE_W * accum[0];
        float pose_prior_loss = POSE_W * pose;
        float hand_pose_prior_loss = HANDPOSE_W * hand;
        out[0] = contactloss + insideloss + outsideloss + pose_prior_loss +
                 hand_pose_prior_loss + angle_loss + hand_contact_loss;
    }
}

extern "C" void kernel_launch(void* const* d_in, const int* in_sizes, int n_in,
                              void* d_out, int out_size, void* d_ws, size_t ws_size,
                              hipStream_t stream)
{
    const float* verts    = (const float*)d_in[0];
    const float* v2v_min  = (const float*)d_in[1];
    const float* geodist  = (const float*)d_in[2];
    const float* hcpw     = (const float*)d_in[3];
    const float* bp       = (const float*)d_in[4];
    const float* ip       = (const float*)d_in[5];
    const float* lh       = (const float*)d_in[6];
    const float* rh       = (const float*)d_in[7];
    const float* iverts   = (const float*)d_in[8];
    const int*   vmi      = (const int*)d_in[9];
    const int*   exterior = (const int*)d_in[10];
    const int*   ds       = (const int*)d_in[11];
    const int*   ivc      = (const int*)d_in[12];
    const int*   hcp      = (const int*)d_in[13];
    const int*   faces    = (const int*)d_in[14];

    int NV  = in_sizes[1];
    int NDS = in_sizes[11];
    int NC  = in_sizes[12];
    int HA  = in_sizes[13] / 2;
    int NF  = in_sizes[14] / 3;

    float* accum  = (float*)d_ws;                 // 32 floats
    float* vn     = accum + 32;                   // 3*NV floats
    int*   inside = (int*)(vn + 3 * (size_t)NV);  // NV ints
    float* gdi    = (float*)(inside + NV);        // NV floats

    size_t zbytes = (size_t)(32 + 4 * (size_t)NV) * sizeof(float); // accum+vn+inside
    hipMemsetAsync(d_ws, 0, zbytes, stream);

    k_gdi<<<NV, 256, 0, stream>>>(geodist, ivc, verts, iverts, gdi, accum, NV, NC);

    int nmax = (NF > NDS) ? NF : NDS;
    k_faces<<<(nmax + 255) / 256, 256, 0, stream>>>(verts, faces, vn, ds, exterior, inside, NF, NDS);

    k_normalize<<<(NV + 255) / 256, 256, 0, stream>>>(vn, accum, NV);

    k_terms<<<(NV + 255) / 256, 256, 0, stream>>>(v2v_min, vmi, vn, gdi, ds, exterior,
                                                  hcp, hcpw, inside, accum, NV, NDS, HA);

    k_final<<<1, 128, 0, stream>>>(accum, bp, ip, lh, rh, (float*)d_out);
}